// Round 2
// baseline (180.068 us; speedup 1.0000x reference)
//
#include <hip/hip_runtime.h>

// PointMassModel: X' = [v, a - g, c*(u - a)], RK4 x 8 substeps, h = DT/8.
// Linear constant-coefficient ODE => the whole 8-substep RK4 integration is
// exactly an affine map  s8 = P8 * s + Ku * u + G  (per axis), with 3x3 P8,
// per-row u-coefficients Ku, and additive gravity constants G, computed
// host-side in double precision. Kernel is a pure streaming transform.
//
// R2 structure: NO LDS, NO barriers. Each thread owns 4 consecutive envs =
// 9 contiguous float4 loads + 9 contiguous float4 stores (stride-144B across
// lanes; every 64B line touched exactly once over the unroll, so no
// redundant HBM traffic — only extra TA address processing, which models
// below the HBM floor).

#define THREADS 256

struct Coeffs {
    float P00, P01, P02;
    float P10, P11, P12;
    float P20, P21, P22;
    float Ku0, Ku1, Ku2;   // u coefficient per row
    float G0,  G1,  G2;    // additive gravity constant per row (z-axis only)
};

__global__ __launch_bounds__(THREADS)
void pointmass_kernel(const float* __restrict__ X0,
                      const float* __restrict__ U,
                      float* __restrict__ Out,
                      int envTotal, Coeffs cf) {
    const int tid = blockIdx.x * THREADS + threadIdx.x;
    const int envBase = tid * 4;
    if (envBase >= envTotal) return;

    if (envBase + 4 <= envTotal) {
        // ---- fast path: 4 whole envs, all-vector ----
        const float4* x4 = (const float4*)(X0 + (size_t)envBase * 9);
        const float4* u4 = (const float4*)(U  + (size_t)envBase * 3);
        float4*       o4 = (float4*)(Out + (size_t)envBase * 9);

        float4 xin[9], uin[3], oo[9];
        #pragma unroll
        for (int j = 0; j < 9; ++j) xin[j] = x4[j];
        #pragma unroll
        for (int j = 0; j < 3; ++j) uin[j] = u4[j];

        const float* x = (const float*)xin;
        const float* u = (const float*)uin;
        float*       o = (float*)oo;

        #pragma unroll
        for (int m = 0; m < 4; ++m) {
            #pragma unroll
            for (int k = 0; k < 3; ++k) {
                const float p  = x[9 * m + k];
                const float v  = x[9 * m + 3 + k];
                const float a  = x[9 * m + 6 + k];
                const float uu = u[3 * m + k];
                float r0 = cf.P00 * p + cf.P01 * v + cf.P02 * a + cf.Ku0 * uu;
                float r1 = cf.P10 * p + cf.P11 * v + cf.P12 * a + cf.Ku1 * uu;
                float r2 = cf.P20 * p + cf.P21 * v + cf.P22 * a + cf.Ku2 * uu;
                if (k == 2) { r0 += cf.G0; r1 += cf.G1; r2 += cf.G2; }
                o[9 * m + k]     = r0;
                o[9 * m + 3 + k] = r1;
                o[9 * m + 6 + k] = r2;
            }
        }

        #pragma unroll
        for (int j = 0; j < 9; ++j) o4[j] = oo[j];
    } else {
        // ---- tail path: scalar per env (unused for N=2^21, but safe) ----
        for (int e = envBase; e < envTotal; ++e) {
            float p[3], v[3], a[3], uu[3];
            for (int k = 0; k < 3; ++k) {
                p[k]  = X0[(size_t)e * 9 + k];
                v[k]  = X0[(size_t)e * 9 + 3 + k];
                a[k]  = X0[(size_t)e * 9 + 6 + k];
                uu[k] = U[(size_t)e * 3 + k];
            }
            for (int k = 0; k < 3; ++k) {
                float r0 = cf.P00 * p[k] + cf.P01 * v[k] + cf.P02 * a[k] + cf.Ku0 * uu[k];
                float r1 = cf.P10 * p[k] + cf.P11 * v[k] + cf.P12 * a[k] + cf.Ku1 * uu[k];
                float r2 = cf.P20 * p[k] + cf.P21 * v[k] + cf.P22 * a[k] + cf.Ku2 * uu[k];
                if (k == 2) { r0 += cf.G0; r1 += cf.G1; r2 += cf.G2; }
                Out[(size_t)e * 9 + k]     = r0;
                Out[(size_t)e * 9 + 3 + k] = r1;
                Out[(size_t)e * 9 + 6 + k] = r2;
            }
        }
    }
}

// ---------------- host-side coefficient computation ----------------
static void mat3_mul(const double A[3][3], const double B[3][3], double C[3][3]) {
    for (int i = 0; i < 3; ++i)
        for (int j = 0; j < 3; ++j) {
            double s = 0.0;
            for (int k = 0; k < 3; ++k) s += A[i][k] * B[k][j];
            C[i][j] = s;
        }
}
static void mat3_copy(const double A[3][3], double B[3][3]) {
    for (int i = 0; i < 3; ++i) for (int j = 0; j < 3; ++j) B[i][j] = A[i][j];
}

extern "C" void kernel_launch(void* const* d_in, const int* in_sizes, int n_in,
                              void* d_out, int out_size, void* d_ws, size_t ws_size,
                              hipStream_t stream) {
    const float* X0 = (const float*)d_in[0];
    const float* U  = (const float*)d_in[1];
    float* Out = (float*)d_out;
    const int envTotal = in_sizes[0] / 9;

    // --- build RK4 closed-form coefficients in double ---
    const double DT = 0.02;
    const double h = DT / 8.0;
    const double c = 0.5 / DT;                 // LMBDA / DT = 25
    double hA[3][3] = {{0, h, 0}, {0, 0, h}, {0, 0, -c * h}};

    double hA2[3][3], hA3[3][3], hA4[3][3];
    mat3_mul(hA, hA, hA2);
    mat3_mul(hA2, hA, hA3);
    mat3_mul(hA3, hA, hA4);

    double P[3][3], Q[3][3];
    for (int i = 0; i < 3; ++i)
        for (int j = 0; j < 3; ++j) {
            const double I = (i == j) ? 1.0 : 0.0;
            P[i][j] = I + hA[i][j] + hA2[i][j] / 2.0 + hA3[i][j] / 6.0 + hA4[i][j] / 24.0;
            Q[i][j] = h * (I + hA[i][j] / 2.0 + hA2[i][j] / 6.0 + hA3[i][j] / 24.0);
        }

    double P2[3][3], P4[3][3], P8[3][3];
    mat3_mul(P, P, P2);
    mat3_mul(P2, P2, P4);
    mat3_mul(P4, P4, P8);

    // S = I + P + ... + P^7 = (I+P)(I+P^2)(I+P^4)
    double IP[3][3], IP2[3][3], IP4[3][3], T[3][3], S[3][3], R[3][3];
    mat3_copy(P, IP);  mat3_copy(P2, IP2);  mat3_copy(P4, IP4);
    for (int i = 0; i < 3; ++i) { IP[i][i] += 1.0; IP2[i][i] += 1.0; IP4[i][i] += 1.0; }
    mat3_mul(IP, IP2, T);
    mat3_mul(T, IP4, S);
    mat3_mul(S, Q, R);

    Coeffs cf;
    cf.P00 = (float)P8[0][0]; cf.P01 = (float)P8[0][1]; cf.P02 = (float)P8[0][2];
    cf.P10 = (float)P8[1][0]; cf.P11 = (float)P8[1][1]; cf.P12 = (float)P8[1][2];
    cf.P20 = (float)P8[2][0]; cf.P21 = (float)P8[2][1]; cf.P22 = (float)P8[2][2];
    cf.Ku0 = (float)(R[0][2] * c); cf.Ku1 = (float)(R[1][2] * c); cf.Ku2 = (float)(R[2][2] * c);
    // gravity enters as w_g = -g_z on the v-row: additive constant per row,
    // z-axis only: G_r = R[r][1] * 9.81  (since a - G_VEC with G_VEC=(0,0,-9.81))
    cf.G0 = (float)(R[0][1] * 9.81);
    cf.G1 = (float)(R[1][1] * 9.81);
    cf.G2 = (float)(R[2][1] * 9.81);

    const int nThreads = (envTotal + 3) / 4;
    const int blocks = (nThreads + THREADS - 1) / THREADS;
    pointmass_kernel<<<blocks, THREADS, 0, stream>>>(X0, U, Out, envTotal, cf);
}

// Round 3
// 166.345 us; speedup vs baseline: 1.0825x; 1.0825x over previous
//
#include <hip/hip_runtime.h>

// PointMassModel: X' = [v, a - g, c*(u - a)], RK4 x 8 substeps, h = DT/8.
// Linear constant-coefficient ODE => whole integration is an affine map
//   s8 = P8 * s + Ku * u + G   (per axis), coefficients host-computed in double.
//
// R3 structure (lessons from R1/R2):
//  - Dense per-instruction coalescing both directions is mandatory (R2: strided
//    per-lane float4 stores caused 1.6x write amplification via partial-sector RMW).
//  - LDS is the transpose medium, but R1's 2-barriers-per-tiny-tile convoyed the
//    memory pipe (2.3 TB/s). Here: persistent blocks, double-buffered input LDS,
//    ONE __syncthreads per tile, register prefetch of the next tile issued right
//    after the barrier, and outputs computed directly in dense slot layout
//    (row-select per element) so there is no output LDS round-trip.

#define THREADS 256
#define TILE_ENVS 256                 // 2304 floats X, 768 floats U per tile
#define TILE_XF   (TILE_ENVS * 9)     // 2304
#define TILE_UF   (TILE_ENVS * 3)     // 768
#define TILE_X4   (TILE_XF / 4)       // 576 float4 slots
#define TILE_U4   (TILE_UF / 4)       // 192

struct Coeffs {
    float P00, P01, P02;
    float P10, P11, P12;
    float P20, P21, P22;
    float Ku0, Ku1, Ku2;   // u coefficient per row
    float G0,  G1,  G2;    // additive gravity constant per row (z-axis only)
};

__device__ __forceinline__ float compute_elem(const float* __restrict__ sx,
                                              const float* __restrict__ su,
                                              int gi, const Coeffs& cf) {
    // gi: tile-local flat output element index in [0, 2304)
    const int e = (unsigned)gi / 9u;       // env within tile (magic-mul)
    const int c = gi - 9 * e;              // component 0..8
    const int r = (unsigned)c / 3u;        // row 0..2 (p/v/a)
    const int k = c - 3 * r;               // axis 0..2
    const float p = sx[e * 9 + k];
    const float v = sx[e * 9 + 3 + k];
    const float a = sx[e * 9 + 6 + k];
    const float u = su[e * 3 + k];
    // branchless row-coefficient select
    const float A  = (r == 0) ? cf.P00 : ((r == 1) ? cf.P10 : cf.P20);
    const float B  = (r == 0) ? cf.P01 : ((r == 1) ? cf.P11 : cf.P21);
    const float C  = (r == 0) ? cf.P02 : ((r == 1) ? cf.P12 : cf.P22);
    const float Ku = (r == 0) ? cf.Ku0 : ((r == 1) ? cf.Ku1 : cf.Ku2);
    const float Gr = (r == 0) ? cf.G0  : ((r == 1) ? cf.G1  : cf.G2);
    float res = A * p + B * v + C * a + Ku * u;
    if (k == 2) res += Gr;                 // gravity only on z axis
    return res;
}

__global__ __launch_bounds__(THREADS)
void pointmass_kernel(const float* __restrict__ X0,
                      const float* __restrict__ U,
                      float* __restrict__ Out,
                      int envTotal, int numTiles, Coeffs cf) {
    __shared__ float sX[2][TILE_XF];   // 2 x 9216 B
    __shared__ float sU[2][TILE_UF];   // 2 x 3072 B   => 24576 B total

    const int t = threadIdx.x;
    const int stride = gridDim.x;

    int tile = blockIdx.x;
    // ---- prefetch tile 0 for this block into registers ----
    float4 rx0, rx1, rx2, ru0;
    {
        const float4* gx = (const float4*)(X0 + (size_t)tile * TILE_XF);
        const float4* gu = (const float4*)(U  + (size_t)tile * TILE_UF);
        rx0 = gx[t];
        rx1 = gx[t + 256];
        if (t < TILE_X4 - 512) rx2 = gx[t + 512];       // t < 64
        if (t < TILE_U4)       ru0 = gu[t];             // t < 192
    }

    int buf = 0;
    for (; tile < numTiles; tile += stride) {
        // ---- stage prefetched registers into LDS (dense b128 writes) ----
        float4* lx = (float4*)sX[buf];
        float4* lu = (float4*)sU[buf];
        lx[t]       = rx0;
        lx[t + 256] = rx1;
        if (t < TILE_X4 - 512) lx[t + 512] = rx2;
        if (t < TILE_U4)       lu[t]       = ru0;

        __syncthreads();   // only barrier per tile

        // ---- issue prefetch for next tile (hidden behind compute+store) ----
        const int nt = tile + stride;
        if (nt < numTiles) {                            // block-uniform branch
            const float4* gx = (const float4*)(X0 + (size_t)nt * TILE_XF);
            const float4* gu = (const float4*)(U  + (size_t)nt * TILE_UF);
            rx0 = gx[t];
            rx1 = gx[t + 256];
            if (t < TILE_X4 - 512) rx2 = gx[t + 512];
            if (t < TILE_U4)       ru0 = gu[t];
        }

        // ---- compute output slots directly in dense layout, store ----
        const float* sx = sX[buf];
        const float* su = sU[buf];
        float4* o4 = (float4*)(Out + (size_t)tile * TILE_XF);

        {
            const int s = t;
            float4 o;
            o.x = compute_elem(sx, su, 4 * s + 0, cf);
            o.y = compute_elem(sx, su, 4 * s + 1, cf);
            o.z = compute_elem(sx, su, 4 * s + 2, cf);
            o.w = compute_elem(sx, su, 4 * s + 3, cf);
            o4[s] = o;
        }
        {
            const int s = t + 256;
            float4 o;
            o.x = compute_elem(sx, su, 4 * s + 0, cf);
            o.y = compute_elem(sx, su, 4 * s + 1, cf);
            o.z = compute_elem(sx, su, 4 * s + 2, cf);
            o.w = compute_elem(sx, su, 4 * s + 3, cf);
            o4[s] = o;
        }
        if (t < TILE_X4 - 512) {                        // t < 64, wave-0 uniform
            const int s = t + 512;
            float4 o;
            o.x = compute_elem(sx, su, 4 * s + 0, cf);
            o.y = compute_elem(sx, su, 4 * s + 1, cf);
            o.z = compute_elem(sx, su, 4 * s + 2, cf);
            o.w = compute_elem(sx, su, 4 * s + 3, cf);
            o4[s] = o;
        }

        buf ^= 1;
    }

    // ---- remainder envs (envTotal % 256), scalar path; empty for N=2^21 ----
    const int remBase = numTiles * TILE_ENVS;
    const int rem = envTotal - remBase;
    if (rem > 0 && blockIdx.x == 0 && t < rem) {
        const int e = remBase + t;
        float p[3], v[3], a[3], uu[3];
        for (int k = 0; k < 3; ++k) {
            p[k]  = X0[(size_t)e * 9 + k];
            v[k]  = X0[(size_t)e * 9 + 3 + k];
            a[k]  = X0[(size_t)e * 9 + 6 + k];
            uu[k] = U[(size_t)e * 3 + k];
        }
        for (int k = 0; k < 3; ++k) {
            float r0 = cf.P00 * p[k] + cf.P01 * v[k] + cf.P02 * a[k] + cf.Ku0 * uu[k];
            float r1 = cf.P10 * p[k] + cf.P11 * v[k] + cf.P12 * a[k] + cf.Ku1 * uu[k];
            float r2 = cf.P20 * p[k] + cf.P21 * v[k] + cf.P22 * a[k] + cf.Ku2 * uu[k];
            if (k == 2) { r0 += cf.G0; r1 += cf.G1; r2 += cf.G2; }
            Out[(size_t)e * 9 + k]     = r0;
            Out[(size_t)e * 9 + 3 + k] = r1;
            Out[(size_t)e * 9 + 6 + k] = r2;
        }
    }
}

// ---------------- host-side coefficient computation ----------------
static void mat3_mul(const double A[3][3], const double B[3][3], double C[3][3]) {
    for (int i = 0; i < 3; ++i)
        for (int j = 0; j < 3; ++j) {
            double s = 0.0;
            for (int k = 0; k < 3; ++k) s += A[i][k] * B[k][j];
            C[i][j] = s;
        }
}
static void mat3_copy(const double A[3][3], double B[3][3]) {
    for (int i = 0; i < 3; ++i) for (int j = 0; j < 3; ++j) B[i][j] = A[i][j];
}

extern "C" void kernel_launch(void* const* d_in, const int* in_sizes, int n_in,
                              void* d_out, int out_size, void* d_ws, size_t ws_size,
                              hipStream_t stream) {
    const float* X0 = (const float*)d_in[0];
    const float* U  = (const float*)d_in[1];
    float* Out = (float*)d_out;
    const int envTotal = in_sizes[0] / 9;

    // --- build RK4 closed-form coefficients in double ---
    const double DT = 0.02;
    const double h = DT / 8.0;
    const double c = 0.5 / DT;                 // LMBDA / DT = 25
    double hA[3][3] = {{0, h, 0}, {0, 0, h}, {0, 0, -c * h}};

    double hA2[3][3], hA3[3][3], hA4[3][3];
    mat3_mul(hA, hA, hA2);
    mat3_mul(hA2, hA, hA3);
    mat3_mul(hA3, hA, hA4);

    double P[3][3], Q[3][3];
    for (int i = 0; i < 3; ++i)
        for (int j = 0; j < 3; ++j) {
            const double I = (i == j) ? 1.0 : 0.0;
            P[i][j] = I + hA[i][j] + hA2[i][j] / 2.0 + hA3[i][j] / 6.0 + hA4[i][j] / 24.0;
            Q[i][j] = h * (I + hA[i][j] / 2.0 + hA2[i][j] / 6.0 + hA3[i][j] / 24.0);
        }

    double P2[3][3], P4[3][3], P8[3][3];
    mat3_mul(P, P, P2);
    mat3_mul(P2, P2, P4);
    mat3_mul(P4, P4, P8);

    // S = I + P + ... + P^7 = (I+P)(I+P^2)(I+P^4)
    double IP[3][3], IP2[3][3], IP4[3][3], T[3][3], S[3][3], R[3][3];
    mat3_copy(P, IP);  mat3_copy(P2, IP2);  mat3_copy(P4, IP4);
    for (int i = 0; i < 3; ++i) { IP[i][i] += 1.0; IP2[i][i] += 1.0; IP4[i][i] += 1.0; }
    mat3_mul(IP, IP2, T);
    mat3_mul(T, IP4, S);
    mat3_mul(S, Q, R);

    Coeffs cf;
    cf.P00 = (float)P8[0][0]; cf.P01 = (float)P8[0][1]; cf.P02 = (float)P8[0][2];
    cf.P10 = (float)P8[1][0]; cf.P11 = (float)P8[1][1]; cf.P12 = (float)P8[1][2];
    cf.P20 = (float)P8[2][0]; cf.P21 = (float)P8[2][1]; cf.P22 = (float)P8[2][2];
    cf.Ku0 = (float)(R[0][2] * c); cf.Ku1 = (float)(R[1][2] * c); cf.Ku2 = (float)(R[2][2] * c);
    cf.G0 = (float)(R[0][1] * 9.81);
    cf.G1 = (float)(R[1][1] * 9.81);
    cf.G2 = (float)(R[2][1] * 9.81);

    const int numTiles = envTotal / TILE_ENVS;
    int blocks = numTiles < 1536 ? (numTiles > 0 ? numTiles : 1) : 1536; // 6 blocks/CU
    pointmass_kernel<<<blocks, THREADS, 0, stream>>>(X0, U, Out, envTotal, numTiles, cf);
}

// Round 4
// 156.028 us; speedup vs baseline: 1.1541x; 1.0661x over previous
//
#include <hip/hip_runtime.h>

// PointMassModel: X' = [v, a - g, c*(u - a)], RK4 x 8 substeps, h = DT/8.
// Linear constant-coefficient ODE => whole integration is the affine map
//   s8 = P8 * s + Ku * u + G  (per axis), coefficients host-computed in double.
//
// R4 structure — lane-triple decomposition, NO LDS / barriers / shuffles:
//   env = 9 floats = 3 x dwordx3. Lane L loads/stores 12 B at float offset 3L,
//   so lanes (3m,3m+1,3m+2) natively hold (p,v,a) of env m. Lane role r = L%3
//   selects the output row; each lane computes its row's 3-vector and stores it
//   back at the SAME dense offset. p/v/a/u are loaded per-triple with shared
//   addresses (hardware broadcast, L1-served, zero extra HBM).
//   Lessons enforced: dense per-instruction stores (R2: strided stores -> 1.6x
//   write RMW amplification), no LDS gather (R3: bank conflicts + occupancy
//   collapse), no per-tile barriers (R1: memory-pipe convoying at 2.3 TB/s).

#define THREADS 256
#define CHUNK_ENVS 21          // 63 active lanes * 3 floats = 21 envs per wave-chunk
#define CHUNKS_PER_WAVE 4      // consecutive chunks -> contiguous 3 KB region/wave

struct Coeffs {
    float P00, P01, P02;
    float P10, P11, P12;
    float P20, P21, P22;
    float Ku0, Ku1, Ku2;   // u coefficient per row
    float G0,  G1,  G2;    // additive gravity constant per row (z-axis only)
};

struct F3 { float x, y, z; };   // 12 B, 4-B aligned -> global_{load,store}_dwordx3

__global__ __launch_bounds__(THREADS)
void pointmass_kernel(const float* __restrict__ X0,
                      const float* __restrict__ U,
                      float* __restrict__ Out,
                      int envTotal, int chunksTotal, Coeffs cf) {
    const int tid  = blockIdx.x * THREADS + threadIdx.x;
    const int wave = tid >> 6;
    const int lane = tid & 63;
    const int r = lane % 3;        // output row: 0=p, 1=v, 2=a
    const int m = lane / 3;        // triple (env-within-chunk) index; lane 63 -> m=21 (inactive)

    // loop-invariant per-lane row coefficients
    const float A  = (r == 0) ? cf.P00 : ((r == 1) ? cf.P10 : cf.P20);
    const float B  = (r == 0) ? cf.P01 : ((r == 1) ? cf.P11 : cf.P21);
    const float C  = (r == 0) ? cf.P02 : ((r == 1) ? cf.P12 : cf.P22);
    const float Ku = (r == 0) ? cf.Ku0 : ((r == 1) ? cf.Ku1 : cf.Ku2);
    const float G  = (r == 0) ? cf.G0  : ((r == 1) ? cf.G1  : cf.G2);

    const int chunk0 = wave * CHUNKS_PER_WAVE;

    #pragma unroll
    for (int j = 0; j < CHUNKS_PER_WAVE; ++j) {
        const int chunk = chunk0 + j;
        if (chunk >= chunksTotal) break;
        const int envBase = chunk * CHUNK_ENVS;
        const int remEnvs = envTotal - envBase;                 // >= 1 here
        const int actEnvs = remEnvs < CHUNK_ENVS ? remEnvs : CHUNK_ENVS;
        if (lane < 3 * actEnvs) {
            const size_t xoff = (size_t)envBase * 9 + 9 * m;    // triple base
            const F3 p = *(const F3*)(X0 + xoff);               // shared within triple
            const F3 v = *(const F3*)(X0 + xoff + 3);
            const F3 a = *(const F3*)(X0 + xoff + 6);
            const F3 u = *(const F3*)(U + (size_t)(envBase + m) * 3);

            F3 o;
            o.x = A * p.x + B * v.x + C * a.x + Ku * u.x;
            o.y = A * p.y + B * v.y + C * a.y + Ku * u.y;
            o.z = A * p.z + B * v.z + C * a.z + Ku * u.z + G;   // gravity: z only

            // dense store: lane writes 12 B at the same offset pattern it loaded
            *(F3*)(Out + (size_t)envBase * 9 + 3 * lane) = o;
        }
    }
}

// ---------------- host-side coefficient computation ----------------
static void mat3_mul(const double A[3][3], const double B[3][3], double C[3][3]) {
    for (int i = 0; i < 3; ++i)
        for (int j = 0; j < 3; ++j) {
            double s = 0.0;
            for (int k = 0; k < 3; ++k) s += A[i][k] * B[k][j];
            C[i][j] = s;
        }
}
static void mat3_copy(const double A[3][3], double B[3][3]) {
    for (int i = 0; i < 3; ++i) for (int j = 0; j < 3; ++j) B[i][j] = A[i][j];
}

extern "C" void kernel_launch(void* const* d_in, const int* in_sizes, int n_in,
                              void* d_out, int out_size, void* d_ws, size_t ws_size,
                              hipStream_t stream) {
    const float* X0 = (const float*)d_in[0];
    const float* U  = (const float*)d_in[1];
    float* Out = (float*)d_out;
    const int envTotal = in_sizes[0] / 9;

    // --- build RK4 closed-form coefficients in double ---
    const double DT = 0.02;
    const double h = DT / 8.0;
    const double c = 0.5 / DT;                 // LMBDA / DT = 25
    double hA[3][3] = {{0, h, 0}, {0, 0, h}, {0, 0, -c * h}};

    double hA2[3][3], hA3[3][3], hA4[3][3];
    mat3_mul(hA, hA, hA2);
    mat3_mul(hA2, hA, hA3);
    mat3_mul(hA3, hA, hA4);

    double P[3][3], Q[3][3];
    for (int i = 0; i < 3; ++i)
        for (int j = 0; j < 3; ++j) {
            const double I = (i == j) ? 1.0 : 0.0;
            P[i][j] = I + hA[i][j] + hA2[i][j] / 2.0 + hA3[i][j] / 6.0 + hA4[i][j] / 24.0;
            Q[i][j] = h * (I + hA[i][j] / 2.0 + hA2[i][j] / 6.0 + hA3[i][j] / 24.0);
        }

    double P2[3][3], P4[3][3], P8[3][3];
    mat3_mul(P, P, P2);
    mat3_mul(P2, P2, P4);
    mat3_mul(P4, P4, P8);

    // S = I + P + ... + P^7 = (I+P)(I+P^2)(I+P^4)
    double IP[3][3], IP2[3][3], IP4[3][3], T[3][3], S[3][3], R[3][3];
    mat3_copy(P, IP);  mat3_copy(P2, IP2);  mat3_copy(P4, IP4);
    for (int i = 0; i < 3; ++i) { IP[i][i] += 1.0; IP2[i][i] += 1.0; IP4[i][i] += 1.0; }
    mat3_mul(IP, IP2, T);
    mat3_mul(T, IP4, S);
    mat3_mul(S, Q, R);

    Coeffs cf;
    cf.P00 = (float)P8[0][0]; cf.P01 = (float)P8[0][1]; cf.P02 = (float)P8[0][2];
    cf.P10 = (float)P8[1][0]; cf.P11 = (float)P8[1][1]; cf.P12 = (float)P8[1][2];
    cf.P20 = (float)P8[2][0]; cf.P21 = (float)P8[2][1]; cf.P22 = (float)P8[2][2];
    cf.Ku0 = (float)(R[0][2] * c); cf.Ku1 = (float)(R[1][2] * c); cf.Ku2 = (float)(R[2][2] * c);
    cf.G0 = (float)(R[0][1] * 9.81);
    cf.G1 = (float)(R[1][1] * 9.81);
    cf.G2 = (float)(R[2][1] * 9.81);

    const int chunksTotal = (envTotal + CHUNK_ENVS - 1) / CHUNK_ENVS;
    const int wavesNeeded = (chunksTotal + CHUNKS_PER_WAVE - 1) / CHUNKS_PER_WAVE;
    const int blocks = (wavesNeeded + (THREADS / 64) - 1) / (THREADS / 64);
    pointmass_kernel<<<blocks, THREADS, 0, stream>>>(X0, U, Out, envTotal, chunksTotal, cf);
}